// Round 23
// baseline (370.556 us; speedup 1.0000x reference)
//
#include <hip/hip_runtime.h>
#include <stdint.h>

typedef unsigned long long u64;
typedef unsigned int u32;
typedef unsigned short u16;
typedef float f32x4 __attribute__((ext_vector_type(4)));
typedef short s16x8 __attribute__((ext_vector_type(8)));   // bf16 bits as shorts

#define NB 4
#define NL 2048
#define NK 48
#define NRES (NB*NL)      // 8192
#define NEDGE (NRES*NK)   // 393216
#define NF 416
#define LDA 424           // padded feature row (bf16 elems)

// MAP (r0..r22, bit-exact on r18/r19/r20 decodes): d_out is FLOAT32:
//   E   f32 [0, 50331648)   row-major [B][L][K][128]
//   Eidx f32 [50331648, 50724864)
// Validator compares bf16(high-u16 of each f32). Write f32 with f2bf<<16.
#define EIDX_OFF 50331648u

// scratch byte offsets in d_ws (total 3932160 B)
#define WS_ATOMS 0u        // 5 * 8192 * 16B = 655360
#define WS_WB    655360u   // 128*416*2 = 106496
#define WS_PETAB 761856u   // 66*16*2 = 2112
#define WS_EIDX  786432u   // 393216*4
#define WS_DNB   2359296u  // 393216*4

// atom ids: N=0 Ca=1 C=2 O=3 Cb=4 ; PAIRS order from reference
__constant__ int c_PA_r23[24] = {0,2,3,4,1,1,1,1,0,0,0,4,4,3,0,2,3,4,2,3,4,2,3,2};
__constant__ int c_PB_r23[24] = {0,2,3,4,0,2,3,4,2,3,4,2,3,2,1,1,1,1,0,0,0,4,4,3};

static __device__ __forceinline__ u16 f2bf(float v) {
    u32 u = __float_as_uint(v);
    u = (u + 0x7fffu + ((u >> 16) & 1u)) >> 16;   // RNE
    return (u16)u;
}
static __device__ __forceinline__ float bfout(float v) {
    return __uint_as_float((u32)f2bf(v) << 16);   // f32 whose high u16 = RNE bf16
}

// np-bit-exact: f32 adds in source order (contract off), IEEE f32 sqrt via f64.
static __device__ __forceinline__ float dist_np(float ax, float ay, float az,
                                                float bx, float by, float bz) {
    #pragma clang fp contract(off)
    float dx = ax - bx, dy = ay - by, dz = az - bz;
    float s = dx * dx;
    s = s + dy * dy;
    s = s + dz * dz;
    s = s + 1e-6f;
    return (float)sqrt((double)s);
}

__global__ __launch_bounds__(256) void k_prep_r23(
        const float* __restrict__ X, const float* __restrict__ edge_w,
        const float* __restrict__ pe_w, const float* __restrict__ pe_b,
        float4* __restrict__ atoms, u16* __restrict__ Wb, u16* __restrict__ petab) {
    int bid = blockIdx.x, tid = threadIdx.x;
    if (bid < 32) {
        int r = (bid << 8) + tid;                       // 8192 residues
        const float4* Xr = (const float4*)(X + (size_t)r * 12);
        float4 q0 = Xr[0], q1 = Xr[1], q2 = Xr[2];
        float Nx=q0.x, Ny=q0.y, Nz=q0.z;
        float Cax=q0.w, Cay=q1.x, Caz=q1.y;
        float Cx=q1.z, Cy=q1.w, Cz=q2.x;
        float Ox=q2.y, Oy=q2.z, Oz=q2.w;
        float bx=Cax-Nx, by=Cay-Ny, bz=Caz-Nz;
        float cx=Cx-Cax, cy=Cy-Cay, cz=Cz-Caz;
        float ax=by*cz-bz*cy, ay=bz*cx-bx*cz, az=bx*cy-by*cx;
        float Cbx = -0.58273431f*ax + 0.56802827f*bx - 0.54067466f*cx + Cax;
        float Cby = -0.58273431f*ay + 0.56802827f*by - 0.54067466f*cy + Cay;
        float Cbz = -0.58273431f*az + 0.56802827f*bz - 0.54067466f*cz + Caz;
        atoms[0*NRES + r] = make_float4(Nx,Ny,Nz,0.f);
        atoms[1*NRES + r] = make_float4(Cax,Cay,Caz,0.f);
        atoms[2*NRES + r] = make_float4(Cx,Cy,Cz,0.f);
        atoms[3*NRES + r] = make_float4(Ox,Oy,Oz,0.f);
        atoms[4*NRES + r] = make_float4(Cbx,Cby,Cbz,0.f);
    } else if (bid < 240) {
        int w = ((bid - 32) << 8) + tid;                // 53248 weights
        Wb[w] = f2bf(edge_w[w]);
    } else {
        int t = ((bid - 240) << 8) + tid;
        if (t < 66 * 16) {                              // petab[d][e] = pe_w[e][d] + pe_b[e]
            int d = t >> 4, e = t & 15;
            petab[t] = f2bf(pe_w[e * 66 + d] + pe_b[e]);
        }
    }
}

// one wave per query row; exact top-48 via strictly-increasing (dist,idx) key scan.
__global__ __launch_bounds__(256) void k_knn_r23(
        const float4* __restrict__ atoms, const float* __restrict__ mask,
        int* __restrict__ eidx, float* __restrict__ dnb, float* __restrict__ outI) {
    __shared__ float4 sca[NL];
    __shared__ float smk[NL];
    int tid = threadIdx.x;
    int b = blockIdx.x >> 9;
    int i0 = (blockIdx.x & 511) << 2;
    for (int j = tid; j < NL; j += 256) {
        sca[j] = atoms[NRES + b * NL + j];   // Ca
        smk[j] = mask[b * NL + j];
    }
    __syncthreads();
    int wid = tid >> 6, lane = tid & 63;
    int il = i0 + wid;
    float4 ci = sca[il];
    float mi = smk[il];
    float dmax = 0.f;
    #pragma unroll
    for (int t = 0; t < 32; ++t) {
        int j = lane + (t << 6);
        float4 cj = sca[j];
        float d = dist_np(ci.x, ci.y, ci.z, cj.x, cj.y, cj.z);
        dmax = fmaxf(dmax, (mi * smk[j]) * d);
    }
    #pragma unroll
    for (int off = 32; off; off >>= 1) dmax = fmaxf(dmax, __shfl_xor(dmax, off));
    u64 key[32];
    #pragma unroll
    for (int t = 0; t < 32; ++t) {
        int j = lane + (t << 6);
        float4 cj = sca[j];
        float d = dist_np(ci.x, ci.y, ci.z, cj.x, cj.y, cj.z);
        float m2 = mi * smk[j];
        float adj = m2 * d + (1.f - m2) * dmax;       // D_adjust (identity when mask==1)
        key[t] = ((u64)__float_as_uint(adj) << 32) | (u32)j;
    }
    u64 prev = 0, res = 0;
    #pragma unroll 1
    for (int it = 0; it < NK; ++it) {
        u64 best = ~0ull;
        #pragma unroll
        for (int t = 0; t < 32; ++t) {
            u64 k = key[t];
            bool c = (k > prev) && (k < best);
            best = c ? k : best;
        }
        #pragma unroll
        for (int off = 32; off; off >>= 1) {
            u32 lo = (u32)best, hi = (u32)(best >> 32);
            u32 olo = (u32)__shfl_xor((int)lo, off);
            u32 ohi = (u32)__shfl_xor((int)hi, off);
            u64 o = ((u64)ohi << 32) | olo;
            best = (o < best) ? o : best;
        }
        if (lane == it) res = best;
        prev = best;
    }
    if (lane < NK) {
        int e = (b * NL + il) * NK + lane;
        int j = (int)(res & 0xffffffffull);
        eidx[e] = j;
        dnb[e] = __uint_as_float((u32)(res >> 32));
        outI[e] = bfout((float)j);                    // E_idx as f32
    }
}

// fused: features (bf16 into LDS) -> 64x128x416 MFMA GEMM -> LayerNorm -> f32 out
__global__ __launch_bounds__(256) void k_edge_r23(
        const float4* __restrict__ atoms, const int* __restrict__ eidx,
        const float* __restrict__ dnb, const int* __restrict__ residx,
        const int* __restrict__ chains, const u16* __restrict__ Wb,
        const u16* __restrict__ petab, const float* __restrict__ ln_s,
        const float* __restrict__ ln_b, float* __restrict__ outF) {
    __shared__ __align__(16) u16 Abuf[64 * LDA];      // 54272 B; reused as C (f32, stride 133)
    __shared__ int srow[64], sjg[64];
    float* Cls = (float*)Abuf;
    int tid = threadIdx.x;
    int e0 = blockIdx.x << 6;

    if (tid < 64) {
        int e = e0 + tid;
        int row = e / NK;
        int b = row >> 11;
        int j = eidx[e];
        int jg = (b << 11) + j;
        srow[tid] = row;
        sjg[tid] = jg;
        int d = residx[row] - residx[jg] + 32;
        d = d < 0 ? 0 : (d > 64 ? 64 : d);
        d = (chains[row] == chains[jg]) ? d : 65;
        const uint4* src = (const uint4*)(petab + d * 16);
        uint4* dst = (uint4*)(Abuf + tid * LDA);      // cols 0..15 = E_pos
        dst[0] = src[0];
        dst[1] = src[1];
    }
    __syncthreads();

    #pragma unroll 1
    for (int it = 0; it < 7; ++it) {                  // 64 edges x 25 dist-sets
        int tau = tid + (it << 8);
        if (tau < 1600) {
            int el = tau / 25;
            int s = tau - el * 25;
            float dv;
            if (s == 0) {
                dv = dnb[e0 + el];
            } else {
                float4 pa = atoms[c_PA_r23[s-1] * NRES + srow[el]];
                float4 pb = atoms[c_PB_r23[s-1] * NRES + sjg[el]];
                float dx = pa.x - pb.x, dy = pa.y - pb.y, dz = pa.z - pb.z;
                dv = sqrtf(dx*dx + dy*dy + dz*dz + 1e-6f);
            }
            u32 o[8];
            #pragma unroll
            for (int m = 0; m < 8; ++m) {
                float mu0 = 2.f + (20.f/15.f) * (2*m);
                float mu1 = 2.f + (20.f/15.f) * (2*m+1);
                float a0 = (dv - mu0) * 0.8f;
                float a1 = (dv - mu1) * 0.8f;
                float v0 = __expf(-a0*a0);
                float v1 = __expf(-a1*a1);
                o[m] = (u32)f2bf(v0) | ((u32)f2bf(v1) << 16);
            }
            uint4* dst = (uint4*)(Abuf + el * LDA + 16 + 16 * s);
            dst[0] = make_uint4(o[0], o[1], o[2], o[3]);
            dst[1] = make_uint4(o[4], o[5], o[6], o[7]);
        }
    }
    __syncthreads();

    int w = tid >> 6, lane = tid & 63;
    int lrow = lane & 15, lgrp = lane >> 4;
    f32x4 acc[4][2] = {};
    const u16* wb0 = Wb + (w * 32 + lrow) * NF;       // wave covers cols [32w,32w+32)
    const u16* wb1 = wb0 + 16 * NF;
    #pragma unroll 1
    for (int kk = 0; kk < 13; ++kk) {
        int k0 = kk * 32 + lgrp * 8;
        s16x8 b0 = *(const s16x8*)(wb0 + k0);
        s16x8 b1 = *(const s16x8*)(wb1 + k0);
        #pragma unroll
        for (int mt = 0; mt < 4; ++mt) {
            s16x8 af = *(const s16x8*)(Abuf + (mt * 16 + lrow) * LDA + k0);
            acc[mt][0] = __builtin_amdgcn_mfma_f32_16x16x32_bf16(af, b0, acc[mt][0], 0, 0, 0);
            acc[mt][1] = __builtin_amdgcn_mfma_f32_16x16x32_bf16(af, b1, acc[mt][1], 0, 0, 0);
        }
    }
    __syncthreads();                                   // done reading Abuf
    #pragma unroll
    for (int mt = 0; mt < 4; ++mt) {
        #pragma unroll
        for (int nt = 0; nt < 2; ++nt) {
            #pragma unroll
            for (int r = 0; r < 4; ++r) {
                Cls[(mt * 16 + lgrp * 4 + r) * 133 + w * 32 + nt * 16 + lrow] = acc[mt][nt][r];
            }
        }
    }
    __syncthreads();

    int el = tid >> 2, q = tid & 3;
    float x[32];
    float s = 0.f, sq = 0.f;
    #pragma unroll
    for (int c = 0; c < 32; ++c) {
        float v = Cls[el * 133 + q * 32 + c];
        x[c] = v;
        s += v;
        sq += v * v;
    }
    s += __shfl_xor(s, 1); sq += __shfl_xor(sq, 1);
    s += __shfl_xor(s, 2); sq += __shfl_xor(sq, 2);
    float mean = s * (1.f / 128.f);
    float var = fmaxf(sq * (1.f / 128.f) - mean * mean, 0.f);
    float rstd = 1.f / sqrtf(var + 1e-5f);
    // f32 row write: E[e][c] at outF[e*128 + c]; coalesced across tid
    float* drow = outF + (size_t)(e0 + el) * 128 + q * 32;
    #pragma unroll
    for (int m = 0; m < 32; ++m) {
        int c0 = q * 32 + m;
        float y = (x[m] - mean) * rstd * ln_s[c0] + ln_b[c0];
        y = fminf(20.f, fmaxf(-20.f, y));             // inert clamp (|y|<=11.4 if correct)
        drow[m] = bfout(y);
    }
}

extern "C" void kernel_launch(void* const* d_in, const int* in_sizes, int n_in,
                              void* d_out, int out_size, void* d_ws, size_t ws_size,
                              hipStream_t stream) {
    const float* X        = (const float*)d_in[0];
    const float* mask     = (const float*)d_in[1];
    const int*   residx   = (const int*)d_in[2];
    const int*   chains   = (const int*)d_in[3];
    const float* pe_w     = (const float*)d_in[4];
    const float* pe_b     = (const float*)d_in[5];
    const float* edge_w   = (const float*)d_in[6];
    const float* ln_s     = (const float*)d_in[7];
    const float* ln_b     = (const float*)d_in[8];
    char* ws = (char*)d_ws;
    float4* atoms = (float4*)(ws + WS_ATOMS);
    u16*    Wb    = (u16*)(ws + WS_WB);
    u16*    petab = (u16*)(ws + WS_PETAB);
    int*    eidx  = (int*)(ws + WS_EIDX);
    float*  dnb   = (float*)(ws + WS_DNB);
    float* outF = (float*)d_out;                   // E f32 [0, 50331648)
    float* outI = outF + EIDX_OFF;                 // E_idx f32 [50331648, 50724864)

    k_prep_r23<<<245, 256, 0, stream>>>(X, edge_w, pe_w, pe_b, atoms, Wb, petab);
    k_knn_r23<<<2048, 256, 0, stream>>>(atoms, mask, eidx, dnb, outI);
    k_edge_r23<<<6144, 256, 0, stream>>>(atoms, eidx, dnb, residx, chains, Wb,
                                         petab, ln_s, ln_b, outF);
}

// Round 24
// 292.192 us; speedup vs baseline: 1.2682x; 1.2682x over previous
//
#include <hip/hip_runtime.h>
#include <stdint.h>

typedef unsigned long long u64;
typedef unsigned int u32;
typedef unsigned short u16;
typedef float f32x4 __attribute__((ext_vector_type(4)));
typedef short s16x8 __attribute__((ext_vector_type(8)));   // bf16 bits as shorts

#define NB 4
#define NL 2048
#define NK 48
#define NRES (NB*NL)      // 8192
#define NEDGE (NRES*NK)   // 393216
#define NF 416
#define LDA 424           // padded A row (bf16 elems); 848B = 2-way-free for MFMA reads
#define TS 32             // edge tile (32-tile -> 27.5KB LDS -> 4 blocks/CU)
#define CLS 136           // C stride (f32); 544B row, 16B-aligned, 2-way-free b128 reads

// d_out map (r23-verified): E f32 [0, 50331648) row-major [B][L][K][128];
// E_idx f32 [50331648, 50724864). Validator compares bf16(high u16 of f32).
#define EIDX_OFF 50331648u

// scratch in d_ws
#define WS_ATOMS 0u        // 5*8192*16 = 655360
#define WS_WB    655360u   // 128*416*2 = 106496
#define WS_PETAB 761856u   // 66*16*2 = 2112
#define WS_EIDX  786432u   // 393216*4
#define WS_DNB   2359296u  // 393216*4

__constant__ int c_PA_r24[24] = {0,2,3,4,1,1,1,1,0,0,0,4,4,3,0,2,3,4,2,3,4,2,3,2};
__constant__ int c_PB_r24[24] = {0,2,3,4,0,2,3,4,2,3,4,2,3,2,1,1,1,1,0,0,0,4,4,3};

static __device__ __forceinline__ u16 f2bf(float v) {       // exact RNE (E_idx path)
    u32 u = __float_as_uint(v);
    u = (u + 0x7fffu + ((u >> 16) & 1u)) >> 16;
    return (u16)u;
}
static __device__ __forceinline__ float bfout(float v) {
    return __uint_as_float((u32)f2bf(v) << 16);
}
static __device__ __forceinline__ float bftrunc(float v) {  // cheap bf16 (E path, 1 inst)
    return __uint_as_float(__float_as_uint(v) & 0xffff0000u);
}
static __device__ __forceinline__ u16 bt16(float v) {       // truncated bf16 bits
    return (u16)(__float_as_uint(v) >> 16);
}

// np-bit-exact distance: contract-off f32 adds, IEEE f32 sqrt via f64.
static __device__ __forceinline__ float dist_np(float ax, float ay, float az,
                                                float bx, float by, float bz) {
    #pragma clang fp contract(off)
    float dx = ax - bx, dy = ay - by, dz = az - bz;
    float s = dx * dx;
    s = s + dy * dy;
    s = s + dz * dz;
    s = s + 1e-6f;
    return (float)sqrt((double)s);
}

__global__ __launch_bounds__(256) void k_prep_r24(
        const float* __restrict__ X, const float* __restrict__ edge_w,
        const float* __restrict__ pe_w, const float* __restrict__ pe_b,
        float4* __restrict__ atoms, u16* __restrict__ Wb, u16* __restrict__ petab) {
    int bid = blockIdx.x, tid = threadIdx.x;
    if (bid < 32) {
        int r = (bid << 8) + tid;
        const float4* Xr = (const float4*)(X + (size_t)r * 12);
        float4 q0 = Xr[0], q1 = Xr[1], q2 = Xr[2];
        float Nx=q0.x, Ny=q0.y, Nz=q0.z;
        float Cax=q0.w, Cay=q1.x, Caz=q1.y;
        float Cx=q1.z, Cy=q1.w, Cz=q2.x;
        float Ox=q2.y, Oy=q2.z, Oz=q2.w;
        float bx=Cax-Nx, by=Cay-Ny, bz=Caz-Nz;
        float cx=Cx-Cax, cy=Cy-Cay, cz=Cz-Caz;
        float ax=by*cz-bz*cy, ay=bz*cx-bx*cz, az=bx*cy-by*cx;
        float Cbx = -0.58273431f*ax + 0.56802827f*bx - 0.54067466f*cx + Cax;
        float Cby = -0.58273431f*ay + 0.56802827f*by - 0.54067466f*cy + Cay;
        float Cbz = -0.58273431f*az + 0.56802827f*bz - 0.54067466f*cz + Caz;
        atoms[0*NRES + r] = make_float4(Nx,Ny,Nz,0.f);
        atoms[1*NRES + r] = make_float4(Cax,Cay,Caz,0.f);
        atoms[2*NRES + r] = make_float4(Cx,Cy,Cz,0.f);
        atoms[3*NRES + r] = make_float4(Ox,Oy,Oz,0.f);
        atoms[4*NRES + r] = make_float4(Cbx,Cby,Cbz,0.f);
    } else if (bid < 240) {
        int w = ((bid - 32) << 8) + tid;
        Wb[w] = f2bf(edge_w[w]);
    } else {
        int t = ((bid - 240) << 8) + tid;
        if (t < 66 * 16) {
            int d = t >> 4, e = t & 15;
            petab[t] = f2bf(pe_w[e * 66 + d] + pe_b[e]);
        }
    }
}

// one wave per query row; exact top-48; SINGLE dist pass (key = m2*d, zero-keys
// patched to dmax after reduce — bit-identical to m2*d+(1-m2)*dmax for m2 in {0,1}).
__global__ __launch_bounds__(256) void k_knn_r24(
        const float4* __restrict__ atoms, const float* __restrict__ mask,
        int* __restrict__ eidx, float* __restrict__ dnb, float* __restrict__ outI) {
    __shared__ float4 sca[NL];
    __shared__ float smk[NL];
    int tid = threadIdx.x;
    int b = blockIdx.x >> 9;
    int i0 = (blockIdx.x & 511) << 2;
    for (int j = tid; j < NL; j += 256) {
        sca[j] = atoms[NRES + b * NL + j];
        smk[j] = mask[b * NL + j];
    }
    __syncthreads();
    int wid = tid >> 6, lane = tid & 63;
    int il = i0 + wid;
    float4 ci = sca[il];
    float mi = smk[il];
    u64 key[32];
    float dmax = 0.f;
    #pragma unroll
    for (int t = 0; t < 32; ++t) {
        int j = lane + (t << 6);
        float4 cj = sca[j];
        float d = dist_np(ci.x, ci.y, ci.z, cj.x, cj.y, cj.z);
        float md = (mi * smk[j]) * d;          // == d when mask==1; 0 when masked
        dmax = fmaxf(dmax, md);
        key[t] = ((u64)__float_as_uint(md) << 32) | (u32)j;
    }
    #pragma unroll
    for (int off = 32; off; off >>= 1) dmax = fmaxf(dmax, __shfl_xor(dmax, off));
    u64 patch = (u64)__float_as_uint(dmax) << 32;
    #pragma unroll
    for (int t = 0; t < 32; ++t) {             // masked (md==0, since d>1e-3) -> dmax
        if ((u32)(key[t] >> 32) == 0u) key[t] = patch | (u32)(lane + (t << 6));
    }
    u64 prev = 0, res = 0;
    #pragma unroll 1
    for (int it = 0; it < NK; ++it) {
        u64 best = ~0ull;
        #pragma unroll
        for (int t = 0; t < 32; ++t) {
            u64 k = key[t];
            bool c = (k > prev) && (k < best);
            best = c ? k : best;
        }
        #pragma unroll
        for (int off = 32; off; off >>= 1) {
            u32 lo = (u32)best, hi = (u32)(best >> 32);
            u32 olo = (u32)__shfl_xor((int)lo, off);
            u32 ohi = (u32)__shfl_xor((int)hi, off);
            u64 o = ((u64)ohi << 32) | olo;
            best = (o < best) ? o : best;
        }
        if (lane == it) res = best;
        prev = best;
    }
    if (lane < NK) {
        int e = (b * NL + il) * NK + lane;
        int j = (int)(res & 0xffffffffull);
        eidx[e] = j;
        dnb[e] = __uint_as_float((u32)(res >> 32));
        outI[e] = bfout((float)j);
    }
}

// 32-edge tile: features -> 32x128x416 MFMA -> LayerNorm -> f32 out (coalesced)
__global__ __launch_bounds__(256) void k_edge_r24(
        const float4* __restrict__ atoms, const int* __restrict__ eidx,
        const float* __restrict__ dnb, const int* __restrict__ residx,
        const int* __restrict__ chains, const u16* __restrict__ Wb,
        const u16* __restrict__ petab, const float* __restrict__ ln_s,
        const float* __restrict__ ln_b, float* __restrict__ outF) {
    __shared__ __align__(16) u16 Abuf[TS * LDA];      // 27136 B; reused as C (f32, stride 136)
    __shared__ int srow[TS], sjg[TS];
    float* Cls = (float*)Abuf;
    int tid = threadIdx.x;
    int e0 = blockIdx.x << 5;

    if (tid < TS) {
        int e = e0 + tid;
        int row = e / NK;
        int b = row >> 11;
        int j = eidx[e];
        int jg = (b << 11) + j;
        srow[tid] = row;
        sjg[tid] = jg;
        int d = residx[row] - residx[jg] + 32;
        d = d < 0 ? 0 : (d > 64 ? 64 : d);
        d = (chains[row] == chains[jg]) ? d : 65;
        const uint4* src = (const uint4*)(petab + d * 16);
        uint4* dst = (uint4*)(Abuf + tid * LDA);      // cols 0..15 = E_pos
        dst[0] = src[0];
        dst[1] = src[1];
    }
    __syncthreads();

    #pragma unroll 1
    for (int it = 0; it < 4; ++it) {                  // 32 edges x 25 dist-sets = 800
        int tau = tid + (it << 8);
        if (tau < TS * 25) {
            int el = tau / 25;
            int s = tau - el * 25;
            float dv;
            if (s == 0) {
                dv = dnb[e0 + el];
            } else {
                float4 pa = atoms[c_PA_r24[s-1] * NRES + srow[el]];
                float4 pb = atoms[c_PB_r24[s-1] * NRES + sjg[el]];
                float dx = pa.x - pb.x, dy = pa.y - pb.y, dz = pa.z - pb.z;
                dv = sqrtf(dx*dx + dy*dy + dz*dz + 1e-6f);
            }
            u32 o[8];
            #pragma unroll
            for (int m = 0; m < 8; ++m) {
                float mu0 = 2.f + (20.f/15.f) * (2*m);
                float mu1 = 2.f + (20.f/15.f) * (2*m+1);
                float a0 = (dv - mu0) * 0.8f;
                float a1 = (dv - mu1) * 0.8f;
                float v0 = __expf(-a0*a0);
                float v1 = __expf(-a1*a1);
                o[m] = (u32)bt16(v0) | ((u32)bt16(v1) << 16);   // truncated bf16 (16x cheaper)
            }
            uint4* dst = (uint4*)(Abuf + el * LDA + 16 + 16 * s);
            dst[0] = make_uint4(o[0], o[1], o[2], o[3]);
            dst[1] = make_uint4(o[4], o[5], o[6], o[7]);
        }
    }
    __syncthreads();

    int w = tid >> 6, lane = tid & 63;
    int lrow = lane & 15, lgrp = lane >> 4;
    f32x4 acc[2][2] = {};
    const u16* wb0 = Wb + (w * 32 + lrow) * NF;       // wave covers cols [32w, 32w+32)
    const u16* wb1 = wb0 + 16 * NF;
    #pragma unroll 1
    for (int kk = 0; kk < 13; ++kk) {
        int k0 = kk * 32 + lgrp * 8;
        s16x8 b0 = *(const s16x8*)(wb0 + k0);
        s16x8 b1 = *(const s16x8*)(wb1 + k0);
        s16x8 a0 = *(const s16x8*)(Abuf + lrow * LDA + k0);
        s16x8 a1 = *(const s16x8*)(Abuf + (16 + lrow) * LDA + k0);
        acc[0][0] = __builtin_amdgcn_mfma_f32_16x16x32_bf16(a0, b0, acc[0][0], 0, 0, 0);
        acc[0][1] = __builtin_amdgcn_mfma_f32_16x16x32_bf16(a0, b1, acc[0][1], 0, 0, 0);
        acc[1][0] = __builtin_amdgcn_mfma_f32_16x16x32_bf16(a1, b0, acc[1][0], 0, 0, 0);
        acc[1][1] = __builtin_amdgcn_mfma_f32_16x16x32_bf16(a1, b1, acc[1][1], 0, 0, 0);
    }
    __syncthreads();                                   // done reading Abuf
    #pragma unroll
    for (int mt = 0; mt < 2; ++mt) {
        #pragma unroll
        for (int nt = 0; nt < 2; ++nt) {
            #pragma unroll
            for (int r = 0; r < 4; ++r) {
                Cls[(mt * 16 + lgrp * 4 + r) * CLS + w * 32 + nt * 16 + lrow] = acc[mt][nt][r];
            }
        }
    }
    __syncthreads();

    // LN + store: 8 threads/row, 16 cols each (cols t8*4 + 32k + i)
    int row = tid >> 3, t8 = tid & 7;
    const float4* Crow = (const float4*)(Cls + row * CLS);
    float4 xv[4];
    float s = 0.f, sq = 0.f;
    #pragma unroll
    for (int k = 0; k < 4; ++k) {
        float4 v = Crow[t8 + 8 * k];                   // b128, 2-way-free banks
        xv[k] = v;
        s += v.x + v.y + v.z + v.w;
        sq += v.x*v.x + v.y*v.y + v.z*v.z + v.w*v.w;
    }
    s += __shfl_xor(s, 1); sq += __shfl_xor(sq, 1);
    s += __shfl_xor(s, 2); sq += __shfl_xor(sq, 2);
    s += __shfl_xor(s, 4); sq += __shfl_xor(sq, 4);
    float mean = s * (1.f / 128.f);
    float var = fmaxf(sq * (1.f / 128.f) - mean * mean, 0.f);
    float rstd = 1.f / sqrtf(var + 1e-5f);
    float4* drow = (float4*)(outF + (size_t)(e0 + row) * 128);
    #pragma unroll
    for (int k = 0; k < 4; ++k) {
        int c0 = t8 * 4 + 32 * k;
        float4 g = *(const float4*)(ln_s + c0);
        float4 bb = *(const float4*)(ln_b + c0);
        float4 y;
        y.x = bftrunc((xv[k].x - mean) * rstd * g.x + bb.x);
        y.y = bftrunc((xv[k].y - mean) * rstd * g.y + bb.y);
        y.z = bftrunc((xv[k].z - mean) * rstd * g.z + bb.z);
        y.w = bftrunc((xv[k].w - mean) * rstd * g.w + bb.w);
        drow[t8 + 8 * k] = y;                          // 128B-contiguous segments
    }
}

extern "C" void kernel_launch(void* const* d_in, const int* in_sizes, int n_in,
                              void* d_out, int out_size, void* d_ws, size_t ws_size,
                              hipStream_t stream) {
    const float* X        = (const float*)d_in[0];
    const float* mask     = (const float*)d_in[1];
    const int*   residx   = (const int*)d_in[2];
    const int*   chains   = (const int*)d_in[3];
    const float* pe_w     = (const float*)d_in[4];
    const float* pe_b     = (const float*)d_in[5];
    const float* edge_w   = (const float*)d_in[6];
    const float* ln_s     = (const float*)d_in[7];
    const float* ln_b     = (const float*)d_in[8];
    char* ws = (char*)d_ws;
    float4* atoms = (float4*)(ws + WS_ATOMS);
    u16*    Wb    = (u16*)(ws + WS_WB);
    u16*    petab = (u16*)(ws + WS_PETAB);
    int*    eidx  = (int*)(ws + WS_EIDX);
    float*  dnb   = (float*)(ws + WS_DNB);
    float* outF = (float*)d_out;
    float* outI = outF + EIDX_OFF;

    k_prep_r24<<<245, 256, 0, stream>>>(X, edge_w, pe_w, pe_b, atoms, Wb, petab);
    k_knn_r24<<<2048, 256, 0, stream>>>(atoms, mask, eidx, dnb, outI);
    k_edge_r24<<<12288, 256, 0, stream>>>(atoms, eidx, dnb, residx, chains, Wb,
                                          petab, ln_s, ln_b, outF);
}

// Round 25
// 192.637 us; speedup vs baseline: 1.9236x; 1.5168x over previous
//
#include <hip/hip_runtime.h>
#include <stdint.h>

typedef unsigned long long u64;
typedef unsigned int u32;
typedef unsigned short u16;
typedef float f32x4 __attribute__((ext_vector_type(4)));
typedef short s16x8 __attribute__((ext_vector_type(8)));   // bf16 bits as shorts

#define NB 4
#define NL 2048
#define NK 48
#define NRES (NB*NL)      // 8192
#define NEDGE (NRES*NK)   // 393216
#define NF 416
#define LDA 424           // padded A row (bf16); 848B = 2-way-free MFMA reads
#define TS 32             // edge tile
#define CLS 136           // C stride (f32)
#define NHB 1152          // knn histogram buckets (64*18)

// d_out map (r23-verified): E f32 [0, 50331648) [B][L][K][128]; E_idx f32 after.
#define EIDX_OFF 50331648u

// scratch in d_ws
#define WS_ATOMS 0u
#define WS_WB    655360u
#define WS_PETAB 761856u
#define WS_EIDX  786432u
#define WS_DNB   2359296u

__constant__ int c_PA_r25[24] = {0,2,3,4,1,1,1,1,0,0,0,4,4,3,0,2,3,4,2,3,4,2,3,2};
__constant__ int c_PB_r25[24] = {0,2,3,4,0,2,3,4,2,3,4,2,3,2,1,1,1,1,0,0,0,4,4,3};

static __device__ __forceinline__ u16 f2bf(float v) {       // exact RNE
    u32 u = __float_as_uint(v);
    u = (u + 0x7fffu + ((u >> 16) & 1u)) >> 16;
    return (u16)u;
}
static __device__ __forceinline__ float bfout(float v) {
    return __uint_as_float((u32)f2bf(v) << 16);
}
static __device__ __forceinline__ float bftrunc(float v) {
    return __uint_as_float(__float_as_uint(v) & 0xffff0000u);
}
static __device__ __forceinline__ u16 bt16(float v) {
    return (u16)(__float_as_uint(v) >> 16);
}

// np-bit-exact distance: contract-off f32 adds, IEEE f32 sqrt via f64.
static __device__ __forceinline__ float dist_np(float ax, float ay, float az,
                                                float bx, float by, float bz) {
    #pragma clang fp contract(off)
    float dx = ax - bx, dy = ay - by, dz = az - bz;
    float s = dx * dx;
    s = s + dy * dy;
    s = s + dz * dz;
    s = s + 1e-6f;
    return (float)sqrt((double)s);
}

__global__ __launch_bounds__(256) void k_prep_r25(
        const float* __restrict__ X, const float* __restrict__ edge_w,
        const float* __restrict__ pe_w, const float* __restrict__ pe_b,
        float4* __restrict__ atoms, u16* __restrict__ Wb, u16* __restrict__ petab) {
    int bid = blockIdx.x, tid = threadIdx.x;
    if (bid < 32) {
        int r = (bid << 8) + tid;
        const float4* Xr = (const float4*)(X + (size_t)r * 12);
        float4 q0 = Xr[0], q1 = Xr[1], q2 = Xr[2];
        float Nx=q0.x, Ny=q0.y, Nz=q0.z;
        float Cax=q0.w, Cay=q1.x, Caz=q1.y;
        float Cx=q1.z, Cy=q1.w, Cz=q2.x;
        float Ox=q2.y, Oy=q2.z, Oz=q2.w;
        float bx=Cax-Nx, by=Cay-Ny, bz=Caz-Nz;
        float cx=Cx-Cax, cy=Cy-Cay, cz=Cz-Caz;
        float ax=by*cz-bz*cy, ay=bz*cx-bx*cz, az=bx*cy-by*cx;
        float Cbx = -0.58273431f*ax + 0.56802827f*bx - 0.54067466f*cx + Cax;
        float Cby = -0.58273431f*ay + 0.56802827f*by - 0.54067466f*cy + Cay;
        float Cbz = -0.58273431f*az + 0.56802827f*bz - 0.54067466f*cz + Caz;
        atoms[0*NRES + r] = make_float4(Nx,Ny,Nz,0.f);
        atoms[1*NRES + r] = make_float4(Cax,Cay,Caz,0.f);
        atoms[2*NRES + r] = make_float4(Cx,Cy,Cz,0.f);
        atoms[3*NRES + r] = make_float4(Ox,Oy,Oz,0.f);
        atoms[4*NRES + r] = make_float4(Cbx,Cby,Cbz,0.f);
    } else if (bid < 240) {
        int w = ((bid - 32) << 8) + tid;
        Wb[w] = f2bf(edge_w[w]);
    } else {
        int t = ((bid - 240) << 8) + tid;
        if (t < 66 * 16) {
            int d = t >> 4, e = t & 15;
            petab[t] = f2bf(pe_w[e * 66 + d] + pe_b[e]);
        }
    }
}

// one wave per row. Exact top-48 via bucket-histogram prefilter + 64-way rank
// sort on (dist_bits, idx) keys; fallback = exact 48-pass scan (rare).
__global__ __launch_bounds__(256) void k_knn_r25(
        const float4* __restrict__ atoms, const float* __restrict__ mask,
        int* __restrict__ eidx, float* __restrict__ dnb, float* __restrict__ outI) {
    __shared__ u32 hist[4][NHB];
    __shared__ u64 cand[4][64];
    int tid = threadIdx.x;
    int wv = tid >> 6, lane = tid & 63;
    int grow = blockIdx.x * 4 + wv;           // global row
    int b = grow >> 11;
    const float4* ca = atoms + NRES + (b << 11);
    const float* mk = mask + (b << 11);

    float4 ci = ca[grow & 2047];
    float mi = mk[grow & 2047];
    u32 adjb[32];
    float dmax = 0.f;
    #pragma unroll
    for (int t = 0; t < 32; ++t) {
        int j = lane + (t << 6);
        float4 cj = ca[j];
        float d = dist_np(ci.x, ci.y, ci.z, cj.x, cj.y, cj.z);
        float md = (mi * mk[j]) * d;          // == d (mask 1) or 0 (masked)
        dmax = fmaxf(dmax, md);
        adjb[t] = __float_as_uint(md);
    }
    #pragma unroll
    for (int off = 32; off; off >>= 1) dmax = fmaxf(dmax, __shfl_xor(dmax, off));
    u32 dmb = __float_as_uint(dmax);
    #pragma unroll
    for (int t = 0; t < 32; ++t) if (adjb[t] == 0u) adjb[t] = dmb;   // exact D_adjust

    // zero hist, init cand
    #pragma unroll
    for (int i = 0; i < 18; ++i) hist[wv][lane * 18 + i] = 0u;
    cand[wv][lane] = ~0ull;
    __syncthreads();

    #pragma unroll
    for (int t = 0; t < 32; ++t) {
        int bk = (int)(adjb[t] >> 16) - 0x3E00;
        bk = bk < 0 ? 0 : (bk > NHB - 1 ? NHB - 1 : bk);
        atomicAdd(&hist[wv][bk], 1u);
    }
    __syncthreads();

    // per-lane segment sum + wave inclusive scan -> threshold bucket B*
    u32 S = 0;
    #pragma unroll
    for (int i = 0; i < 18; ++i) S += hist[wv][lane * 18 + i];
    u32 cum = S;
    #pragma unroll
    for (int off = 1; off < 64; off <<= 1) {
        u32 o = __shfl_up(cum, off);
        if (lane >= off) cum += o;
    }
    u64 bal = __ballot(cum >= NK);
    int first = (int)__ffsll((unsigned long long)bal) - 1;
    u32 cumprev = (first == 0) ? 0u : (u32)__shfl((int)(cum - S), first); // count before segment
    int Bstar = first * 18 + 17;
    u32 c = cumprev;
    #pragma unroll 1
    for (int i = 0; i < 18; ++i) {            // uniform walk (all lanes identical)
        c += hist[wv][first * 18 + i];
        if (c >= NK) { Bstar = first * 18 + i; break; }
    }
    u32 ncand = c;

    bool small = (ncand <= 64u);
    if (small) {
        u32 base = 0;
        #pragma unroll
        for (int t = 0; t < 32; ++t) {
            int bk = (int)(adjb[t] >> 16) - 0x3E00;
            bk = bk < 0 ? 0 : (bk > NHB - 1 ? NHB - 1 : bk);
            bool p = (bk <= Bstar);
            u64 m = __ballot(p);
            if (p) {
                u32 pos = base + (u32)__popcll(m & ((1ull << lane) - 1ull));
                cand[wv][pos] = ((u64)adjb[t] << 32) | (u32)(lane + (t << 6));
            }
            base += (u32)__popcll(m);
        }
    }
    __syncthreads();

    if (small) {
        u64 key = cand[wv][lane];
        u32 klo = (u32)key, khi = (u32)(key >> 32);
        int rank = 0;
        #pragma unroll
        for (int s = 0; s < 64; ++s) {
            u32 olo = (u32)__shfl((int)klo, s);
            u32 ohi = (u32)__shfl((int)khi, s);
            rank += (ohi < khi) || (ohi == khi && olo < klo);
        }
        if (rank < NK) {
            int e = grow * NK + rank;
            int j = (int)klo;
            eidx[e] = j;
            dnb[e] = __uint_as_float(khi);
            outI[e] = bfout((float)j);
        }
    } else {
        // exact 48-pass scan fallback (keys rebuilt on the fly)
        u64 prev = 0, res = 0;
        #pragma unroll 1
        for (int it = 0; it < NK; ++it) {
            u64 best = ~0ull;
            #pragma unroll
            for (int t = 0; t < 32; ++t) {
                u64 k = ((u64)adjb[t] << 32) | (u32)(lane + (t << 6));
                bool cc = (k > prev) && (k < best);
                best = cc ? k : best;
            }
            #pragma unroll
            for (int off = 32; off; off >>= 1) {
                u32 lo = (u32)best, hi = (u32)(best >> 32);
                u32 olo = (u32)__shfl_xor((int)lo, off);
                u32 ohi = (u32)__shfl_xor((int)hi, off);
                u64 o = ((u64)ohi << 32) | olo;
                best = (o < best) ? o : best;
            }
            if (lane == it) res = best;
            prev = best;
        }
        if (lane < NK) {
            int e = grow * NK + lane;
            int j = (int)(res & 0xffffffffull);
            eidx[e] = j;
            dnb[e] = __uint_as_float((u32)(res >> 32));
            outI[e] = bfout((float)j);
        }
    }
}

// 32-edge tile: features -> 32x128x416 MFMA -> LayerNorm -> f32 out (unchanged r24)
__global__ __launch_bounds__(256) void k_edge_r25(
        const float4* __restrict__ atoms, const int* __restrict__ eidx,
        const float* __restrict__ dnb, const int* __restrict__ residx,
        const int* __restrict__ chains, const u16* __restrict__ Wb,
        const u16* __restrict__ petab, const float* __restrict__ ln_s,
        const float* __restrict__ ln_b, float* __restrict__ outF) {
    __shared__ __align__(16) u16 Abuf[TS * LDA];
    __shared__ int srow[TS], sjg[TS];
    float* Cls = (float*)Abuf;
    int tid = threadIdx.x;
    int e0 = blockIdx.x << 5;

    if (tid < TS) {
        int e = e0 + tid;
        int row = e / NK;
        int b = row >> 11;
        int j = eidx[e];
        int jg = (b << 11) + j;
        srow[tid] = row;
        sjg[tid] = jg;
        int d = residx[row] - residx[jg] + 32;
        d = d < 0 ? 0 : (d > 64 ? 64 : d);
        d = (chains[row] == chains[jg]) ? d : 65;
        const uint4* src = (const uint4*)(petab + d * 16);
        uint4* dst = (uint4*)(Abuf + tid * LDA);
        dst[0] = src[0];
        dst[1] = src[1];
    }
    __syncthreads();

    #pragma unroll 1
    for (int it = 0; it < 4; ++it) {
        int tau = tid + (it << 8);
        if (tau < TS * 25) {
            int el = tau / 25;
            int s = tau - el * 25;
            float dv;
            if (s == 0) {
                dv = dnb[e0 + el];
            } else {
                float4 pa = atoms[c_PA_r25[s-1] * NRES + srow[el]];
                float4 pb = atoms[c_PB_r25[s-1] * NRES + sjg[el]];
                float dx = pa.x - pb.x, dy = pa.y - pb.y, dz = pa.z - pb.z;
                dv = sqrtf(dx*dx + dy*dy + dz*dz + 1e-6f);
            }
            u32 o[8];
            #pragma unroll
            for (int m = 0; m < 8; ++m) {
                float mu0 = 2.f + (20.f/15.f) * (2*m);
                float mu1 = 2.f + (20.f/15.f) * (2*m+1);
                float a0 = (dv - mu0) * 0.8f;
                float a1 = (dv - mu1) * 0.8f;
                float v0 = __expf(-a0*a0);
                float v1 = __expf(-a1*a1);
                o[m] = (u32)bt16(v0) | ((u32)bt16(v1) << 16);
            }
            uint4* dst = (uint4*)(Abuf + el * LDA + 16 + 16 * s);
            dst[0] = make_uint4(o[0], o[1], o[2], o[3]);
            dst[1] = make_uint4(o[4], o[5], o[6], o[7]);
        }
    }
    __syncthreads();

    int w = tid >> 6, lane = tid & 63;
    int lrow = lane & 15, lgrp = lane >> 4;
    f32x4 acc[2][2] = {};
    const u16* wb0 = Wb + (w * 32 + lrow) * NF;
    const u16* wb1 = wb0 + 16 * NF;
    #pragma unroll 1
    for (int kk = 0; kk < 13; ++kk) {
        int k0 = kk * 32 + lgrp * 8;
        s16x8 b0 = *(const s16x8*)(wb0 + k0);
        s16x8 b1 = *(const s16x8*)(wb1 + k0);
        s16x8 a0 = *(const s16x8*)(Abuf + lrow * LDA + k0);
        s16x8 a1 = *(const s16x8*)(Abuf + (16 + lrow) * LDA + k0);
        acc[0][0] = __builtin_amdgcn_mfma_f32_16x16x32_bf16(a0, b0, acc[0][0], 0, 0, 0);
        acc[0][1] = __builtin_amdgcn_mfma_f32_16x16x32_bf16(a0, b1, acc[0][1], 0, 0, 0);
        acc[1][0] = __builtin_amdgcn_mfma_f32_16x16x32_bf16(a1, b0, acc[1][0], 0, 0, 0);
        acc[1][1] = __builtin_amdgcn_mfma_f32_16x16x32_bf16(a1, b1, acc[1][1], 0, 0, 0);
    }
    __syncthreads();
    #pragma unroll
    for (int mt = 0; mt < 2; ++mt) {
        #pragma unroll
        for (int nt = 0; nt < 2; ++nt) {
            #pragma unroll
            for (int r = 0; r < 4; ++r) {
                Cls[(mt * 16 + lgrp * 4 + r) * CLS + w * 32 + nt * 16 + lrow] = acc[mt][nt][r];
            }
        }
    }
    __syncthreads();

    int row = tid >> 3, t8 = tid & 7;
    const float4* Crow = (const float4*)(Cls + row * CLS);
    float4 xv[4];
    float s = 0.f, sq = 0.f;
    #pragma unroll
    for (int k = 0; k < 4; ++k) {
        float4 v = Crow[t8 + 8 * k];
        xv[k] = v;
        s += v.x + v.y + v.z + v.w;
        sq += v.x*v.x + v.y*v.y + v.z*v.z + v.w*v.w;
    }
    s += __shfl_xor(s, 1); sq += __shfl_xor(sq, 1);
    s += __shfl_xor(s, 2); sq += __shfl_xor(sq, 2);
    s += __shfl_xor(s, 4); sq += __shfl_xor(sq, 4);
    float mean = s * (1.f / 128.f);
    float var = fmaxf(sq * (1.f / 128.f) - mean * mean, 0.f);
    float rstd = 1.f / sqrtf(var + 1e-5f);
    float4* drow = (float4*)(outF + (size_t)(e0 + row) * 128);
    #pragma unroll
    for (int k = 0; k < 4; ++k) {
        int c0 = t8 * 4 + 32 * k;
        float4 g = *(const float4*)(ln_s + c0);
        float4 bb = *(const float4*)(ln_b + c0);
        float4 y;
        y.x = bftrunc((xv[k].x - mean) * rstd * g.x + bb.x);
        y.y = bftrunc((xv[k].y - mean) * rstd * g.y + bb.y);
        y.z = bftrunc((xv[k].z - mean) * rstd * g.z + bb.z);
        y.w = bftrunc((xv[k].w - mean) * rstd * g.w + bb.w);
        drow[t8 + 8 * k] = y;
    }
}

extern "C" void kernel_launch(void* const* d_in, const int* in_sizes, int n_in,
                              void* d_out, int out_size, void* d_ws, size_t ws_size,
                              hipStream_t stream) {
    const float* X        = (const float*)d_in[0];
    const float* mask     = (const float*)d_in[1];
    const int*   residx   = (const int*)d_in[2];
    const int*   chains   = (const int*)d_in[3];
    const float* pe_w     = (const float*)d_in[4];
    const float* pe_b     = (const float*)d_in[5];
    const float* edge_w   = (const float*)d_in[6];
    const float* ln_s     = (const float*)d_in[7];
    const float* ln_b     = (const float*)d_in[8];
    char* ws = (char*)d_ws;
    float4* atoms = (float4*)(ws + WS_ATOMS);
    u16*    Wb    = (u16*)(ws + WS_WB);
    u16*    petab = (u16*)(ws + WS_PETAB);
    int*    eidx  = (int*)(ws + WS_EIDX);
    float*  dnb   = (float*)(ws + WS_DNB);
    float* outF = (float*)d_out;
    float* outI = outF + EIDX_OFF;

    k_prep_r25<<<245, 256, 0, stream>>>(X, edge_w, pe_w, pe_b, atoms, Wb, petab);
    k_knn_r25<<<2048, 256, 0, stream>>>(atoms, mask, eidx, dnb, outI);
    k_edge_r25<<<12288, 256, 0, stream>>>(atoms, eidx, dnb, residx, chains, Wb,
                                          petab, ln_s, ln_b, outF);
}

// Round 26
// 187.552 us; speedup vs baseline: 1.9757x; 1.0271x over previous
//
#include <hip/hip_runtime.h>
#include <stdint.h>

typedef unsigned long long u64;
typedef unsigned int u32;
typedef unsigned short u16;
typedef float f32x4 __attribute__((ext_vector_type(4)));
typedef short s16x8 __attribute__((ext_vector_type(8)));   // bf16 bits as shorts

#define NB 4
#define NL 2048
#define NK 48
#define NRES (NB*NL)      // 8192
#define NEDGE (NRES*NK)   // 393216
#define NF 416
#define LDA 424           // padded A row (bf16); 848B stride
#define TS 32             // edge tile
#define CLS 136           // C scratch stride (f32)
#define NHB 1152          // knn histogram buckets

#define EIDX_OFF 50331648u   // d_out: E f32 [0,50331648), E_idx f32 after (r23-verified)

// scratch in d_ws
#define WS_ATOMS 0u
#define WS_WB    655360u
#define WS_PETAB 761856u
#define WS_EIDX  786432u
#define WS_DNB   2359296u

__constant__ int c_PA_r26[24] = {0,2,3,4,1,1,1,1,0,0,0,4,4,3,0,2,3,4,2,3,4,2,3,2};
__constant__ int c_PB_r26[24] = {0,2,3,4,0,2,3,4,2,3,4,2,3,2,1,1,1,1,0,0,0,4,4,3};

static __device__ __forceinline__ u16 f2bf(float v) {       // exact RNE (E_idx)
    u32 u = __float_as_uint(v);
    u = (u + 0x7fffu + ((u >> 16) & 1u)) >> 16;
    return (u16)u;
}
static __device__ __forceinline__ float bfout(float v) {
    return __uint_as_float((u32)f2bf(v) << 16);
}
static __device__ __forceinline__ float bftrunc(float v) {
    return __uint_as_float(__float_as_uint(v) & 0xffff0000u);
}
static __device__ __forceinline__ u16 bt16(float v) {
    return (u16)(__float_as_uint(v) >> 16);
}
static __device__ __forceinline__ float fsqrt_hw(float x) { // v_sqrt_f32, ~1ulp
    float r; asm("v_sqrt_f32 %0, %1" : "=v"(r) : "v"(x)); return r;
}

// np-bit-exact distance (knn path): contract-off f32 adds, IEEE sqrt via f64.
static __device__ __forceinline__ float dist_np(float ax, float ay, float az,
                                                float bx, float by, float bz) {
    #pragma clang fp contract(off)
    float dx = ax - bx, dy = ay - by, dz = az - bz;
    float s = dx * dx;
    s = s + dy * dy;
    s = s + dz * dz;
    s = s + 1e-6f;
    return (float)sqrt((double)s);
}

__global__ __launch_bounds__(256) void k_prep_r26(
        const float* __restrict__ X, const float* __restrict__ edge_w,
        const float* __restrict__ pe_w, const float* __restrict__ pe_b,
        float4* __restrict__ atoms, u16* __restrict__ Wb, u16* __restrict__ petab) {
    int bid = blockIdx.x, tid = threadIdx.x;
    if (bid < 32) {
        int r = (bid << 8) + tid;
        const float4* Xr = (const float4*)(X + (size_t)r * 12);
        float4 q0 = Xr[0], q1 = Xr[1], q2 = Xr[2];
        float Nx=q0.x, Ny=q0.y, Nz=q0.z;
        float Cax=q0.w, Cay=q1.x, Caz=q1.y;
        float Cx=q1.z, Cy=q1.w, Cz=q2.x;
        float Ox=q2.y, Oy=q2.z, Oz=q2.w;
        float bx=Cax-Nx, by=Cay-Ny, bz=Caz-Nz;
        float cx=Cx-Cax, cy=Cy-Cay, cz=Cz-Caz;
        float ax=by*cz-bz*cy, ay=bz*cx-bx*cz, az=bx*cy-by*cx;
        float Cbx = -0.58273431f*ax + 0.56802827f*bx - 0.54067466f*cx + Cax;
        float Cby = -0.58273431f*ay + 0.56802827f*by - 0.54067466f*cy + Cay;
        float Cbz = -0.58273431f*az + 0.56802827f*bz - 0.54067466f*cz + Caz;
        atoms[0*NRES + r] = make_float4(Nx,Ny,Nz,0.f);
        atoms[1*NRES + r] = make_float4(Cax,Cay,Caz,0.f);
        atoms[2*NRES + r] = make_float4(Cx,Cy,Cz,0.f);
        atoms[3*NRES + r] = make_float4(Ox,Oy,Oz,0.f);
        atoms[4*NRES + r] = make_float4(Cbx,Cby,Cbz,0.f);
    } else if (bid < 240) {
        int w = ((bid - 32) << 8) + tid;
        Wb[w] = f2bf(edge_w[w]);
    } else {
        int t = ((bid - 240) << 8) + tid;
        if (t < 66 * 16) {
            int d = t >> 4, e = t & 15;
            petab[t] = f2bf(pe_w[e * 66 + d] + pe_b[e]);
        }
    }
}

// unchanged r25: histogram prefilter + 64-way rank sort (exact), scan fallback
__global__ __launch_bounds__(256) void k_knn_r26(
        const float4* __restrict__ atoms, const float* __restrict__ mask,
        int* __restrict__ eidx, float* __restrict__ dnb, float* __restrict__ outI) {
    __shared__ u32 hist[4][NHB];
    __shared__ u64 cand[4][64];
    int tid = threadIdx.x;
    int wv = tid >> 6, lane = tid & 63;
    int grow = blockIdx.x * 4 + wv;
    int b = grow >> 11;
    const float4* ca = atoms + NRES + (b << 11);
    const float* mk = mask + (b << 11);

    float4 ci = ca[grow & 2047];
    float mi = mk[grow & 2047];
    u32 adjb[32];
    float dmax = 0.f;
    #pragma unroll
    for (int t = 0; t < 32; ++t) {
        int j = lane + (t << 6);
        float4 cj = ca[j];
        float d = dist_np(ci.x, ci.y, ci.z, cj.x, cj.y, cj.z);
        float md = (mi * mk[j]) * d;
        dmax = fmaxf(dmax, md);
        adjb[t] = __float_as_uint(md);
    }
    #pragma unroll
    for (int off = 32; off; off >>= 1) dmax = fmaxf(dmax, __shfl_xor(dmax, off));
    u32 dmb = __float_as_uint(dmax);
    #pragma unroll
    for (int t = 0; t < 32; ++t) if (adjb[t] == 0u) adjb[t] = dmb;

    #pragma unroll
    for (int i = 0; i < 18; ++i) hist[wv][lane * 18 + i] = 0u;
    cand[wv][lane] = ~0ull;
    __syncthreads();

    #pragma unroll
    for (int t = 0; t < 32; ++t) {
        int bk = (int)(adjb[t] >> 16) - 0x3E00;
        bk = bk < 0 ? 0 : (bk > NHB - 1 ? NHB - 1 : bk);
        atomicAdd(&hist[wv][bk], 1u);
    }
    __syncthreads();

    u32 S = 0;
    #pragma unroll
    for (int i = 0; i < 18; ++i) S += hist[wv][lane * 18 + i];
    u32 cum = S;
    #pragma unroll
    for (int off = 1; off < 64; off <<= 1) {
        u32 o = __shfl_up(cum, off);
        if (lane >= off) cum += o;
    }
    u64 bal = __ballot(cum >= NK);
    int first = (int)__ffsll((unsigned long long)bal) - 1;
    u32 cumprev = (first == 0) ? 0u : (u32)__shfl((int)(cum - S), first);
    int Bstar = first * 18 + 17;
    u32 c = cumprev;
    #pragma unroll 1
    for (int i = 0; i < 18; ++i) {
        c += hist[wv][first * 18 + i];
        if (c >= NK) { Bstar = first * 18 + i; break; }
    }
    u32 ncand = c;

    bool small = (ncand <= 64u);
    if (small) {
        u32 base = 0;
        #pragma unroll
        for (int t = 0; t < 32; ++t) {
            int bk = (int)(adjb[t] >> 16) - 0x3E00;
            bk = bk < 0 ? 0 : (bk > NHB - 1 ? NHB - 1 : bk);
            bool p = (bk <= Bstar);
            u64 m = __ballot(p);
            if (p) {
                u32 pos = base + (u32)__popcll(m & ((1ull << lane) - 1ull));
                cand[wv][pos] = ((u64)adjb[t] << 32) | (u32)(lane + (t << 6));
            }
            base += (u32)__popcll(m);
        }
    }
    __syncthreads();

    if (small) {
        u64 key = cand[wv][lane];
        u32 klo = (u32)key, khi = (u32)(key >> 32);
        int rank = 0;
        #pragma unroll
        for (int s = 0; s < 64; ++s) {
            u32 olo = (u32)__shfl((int)klo, s);
            u32 ohi = (u32)__shfl((int)khi, s);
            rank += (ohi < khi) || (ohi == khi && olo < klo);
        }
        if (rank < NK) {
            int e = grow * NK + rank;
            int j = (int)klo;
            eidx[e] = j;
            dnb[e] = __uint_as_float(khi);
            outI[e] = bfout((float)j);
        }
    } else {
        u64 prev = 0, res = 0;
        #pragma unroll 1
        for (int it = 0; it < NK; ++it) {
            u64 best = ~0ull;
            #pragma unroll
            for (int t = 0; t < 32; ++t) {
                u64 k = ((u64)adjb[t] << 32) | (u32)(lane + (t << 6));
                bool cc = (k > prev) && (k < best);
                best = cc ? k : best;
            }
            #pragma unroll
            for (int off = 32; off; off >>= 1) {
                u32 lo = (u32)best, hi = (u32)(best >> 32);
                u32 olo = (u32)__shfl_xor((int)lo, off);
                u32 ohi = (u32)__shfl_xor((int)hi, off);
                u64 o = ((u64)ohi << 32) | olo;
                best = (o < best) ? o : best;
            }
            if (lane == it) res = best;
            prev = best;
        }
        if (lane < NK) {
            int e = grow * NK + lane;
            int j = (int)(res & 0xffffffffull);
            eidx[e] = j;
            dnb[e] = __uint_as_float((u32)(res >> 32));
            outI[e] = bfout((float)j);
        }
    }
}

// RBF via recurrence: RBF_0 and ratio r0 = exp(2*delta*u0 - delta^2), ratio
// decays by q = exp(-2*delta^2) per step (delta = 16/15). 2 exps vs 16.
static __device__ __forceinline__ void rbf_store(u16* dst16, float dv) {
    float u0 = (dv - 2.f) * 0.8f;
    float t = __expf(-u0 * u0);
    float rr = __expf(fminf(2.1333333f * u0 - 1.1377778f, 85.f));  // overflow guard
    const float q = 0.1027349f;
    u16 h[16];
    h[0] = bt16(t);
    #pragma unroll
    for (int m = 1; m < 16; ++m) { t *= rr; rr *= q; h[m] = bt16(t); }
    u32 o[8];
    #pragma unroll
    for (int m = 0; m < 8; ++m) o[m] = (u32)h[2*m] | ((u32)h[2*m+1] << 16);
    uint4* dst = (uint4*)dst16;
    dst[0] = make_uint4(o[0], o[1], o[2], o[3]);
    dst[1] = make_uint4(o[4], o[5], o[6], o[7]);
}

// 32-edge tile: features -> 32x128x416 MFMA -> LayerNorm -> f32 out
__global__ __launch_bounds__(256) void k_edge_r26(
        const float4* __restrict__ atoms, const int* __restrict__ eidx,
        const float* __restrict__ dnb, const int* __restrict__ residx,
        const int* __restrict__ chains, const u16* __restrict__ Wb,
        const u16* __restrict__ petab, const float* __restrict__ ln_s,
        const float* __restrict__ ln_b, float* __restrict__ outF) {
    __shared__ __align__(16) u16 Abuf[TS * LDA];
    __shared__ int srow[TS], sjg[TS];
    float* Cls = (float*)Abuf;
    int tid = threadIdx.x;
    int e0 = blockIdx.x << 5;

    if (tid < TS) {
        int e = e0 + tid;
        int row = e / NK;
        int b = row >> 11;
        int j = eidx[e];
        int jg = (b << 11) + j;
        srow[tid] = row;
        sjg[tid] = jg;
        int d = residx[row] - residx[jg] + 32;
        d = d < 0 ? 0 : (d > 64 ? 64 : d);
        d = (chains[row] == chains[jg]) ? d : 65;
        const uint4* src = (const uint4*)(petab + d * 16);
        uint4* dst = (uint4*)(Abuf + tid * LDA);
        dst[0] = src[0];
        dst[1] = src[1];
    }
    __syncthreads();

    // feature gen: 8 lanes/edge, slots {p, p+8, p+16} (+24 for p==0), no int div
    {
        int el = tid >> 3, p = tid & 7;
        int row = srow[el], jg = sjg[el];
        u16* abase = Abuf + el * LDA + 16;
        #pragma unroll
        for (int jj = 0; jj < 3; ++jj) {
            int s = p + (jj << 3);
            float dv;
            if (s == 0) {
                dv = dnb[e0 + el];
            } else {
                float4 pa = atoms[c_PA_r26[s-1] * NRES + row];
                float4 pb = atoms[c_PB_r26[s-1] * NRES + jg];
                float dx = pa.x - pb.x, dy = pa.y - pb.y, dz = pa.z - pb.z;
                dv = fsqrt_hw(dx*dx + dy*dy + dz*dz + 1e-6f);
            }
            rbf_store(abase + 16 * s, dv);
        }
        if (p == 0) {
            float4 pa = atoms[c_PA_r26[23] * NRES + row];
            float4 pb = atoms[c_PB_r26[23] * NRES + jg];
            float dx = pa.x - pb.x, dy = pa.y - pb.y, dz = pa.z - pb.z;
            rbf_store(abase + 16 * 24, fsqrt_hw(dx*dx + dy*dy + dz*dz + 1e-6f));
        }
    }
    __syncthreads();

    int w = tid >> 6, lane = tid & 63;
    int lrow = lane & 15, lgrp = lane >> 4;
    f32x4 acc[2][2] = {};
    const u16* wb0 = Wb + (w * 32 + lrow) * NF;
    const u16* wb1 = wb0 + 16 * NF;
    #pragma unroll 1
    for (int kk = 0; kk < 13; ++kk) {
        int k0 = kk * 32 + lgrp * 8;
        s16x8 b0 = *(const s16x8*)(wb0 + k0);
        s16x8 b1 = *(const s16x8*)(wb1 + k0);
        s16x8 a0 = *(const s16x8*)(Abuf + lrow * LDA + k0);
        s16x8 a1 = *(const s16x8*)(Abuf + (16 + lrow) * LDA + k0);
        acc[0][0] = __builtin_amdgcn_mfma_f32_16x16x32_bf16(a0, b0, acc[0][0], 0, 0, 0);
        acc[0][1] = __builtin_amdgcn_mfma_f32_16x16x32_bf16(a0, b1, acc[0][1], 0, 0, 0);
        acc[1][0] = __builtin_amdgcn_mfma_f32_16x16x32_bf16(a1, b0, acc[1][0], 0, 0, 0);
        acc[1][1] = __builtin_amdgcn_mfma_f32_16x16x32_bf16(a1, b1, acc[1][1], 0, 0, 0);
    }
    __syncthreads();
    // swizzled C write: col ^ (lgrp<<3) -> 2-way banks (was 4-way)
    #pragma unroll
    for (int mt = 0; mt < 2; ++mt) {
        #pragma unroll
        for (int nt = 0; nt < 2; ++nt) {
            #pragma unroll
            for (int r = 0; r < 4; ++r) {
                int rw = mt * 16 + lgrp * 4 + r;
                int cl = (w * 32 + nt * 16 + lrow) ^ (lgrp << 3);
                Cls[rw * CLS + cl] = acc[mt][nt][r];
            }
        }
    }
    __syncthreads();

    int row = tid >> 3, t8 = tid & 7;
    int swz = ((row >> 2) & 3) << 3;                  // matches writer's lgrp
    const float4* Crow = (const float4*)(Cls + row * CLS);
    float4 xv[4];
    float s = 0.f, sq = 0.f;
    #pragma unroll
    for (int k = 0; k < 4; ++k) {
        float4 v = Crow[t8 + 8 * k];                   // physical read
        xv[k] = v;
        s += v.x + v.y + v.z + v.w;
        sq += v.x*v.x + v.y*v.y + v.z*v.z + v.w*v.w;
    }
    s += __shfl_xor(s, 1); sq += __shfl_xor(sq, 1);
    s += __shfl_xor(s, 2); sq += __shfl_xor(sq, 2);
    s += __shfl_xor(s, 4); sq += __shfl_xor(sq, 4);
    float mean = s * (1.f / 128.f);
    float var = fmaxf(sq * (1.f / 128.f) - mean * mean, 0.f);
    float rstd = 1.f / sqrtf(var + 1e-5f);
    float4* drow = (float4*)(outF + (size_t)(e0 + row) * 128);
    #pragma unroll
    for (int k = 0; k < 4; ++k) {
        int q = t8 + 8 * k;
        int c0 = (q * 4) ^ swz;                        // logical col of this quad
        float4 g = *(const float4*)(ln_s + c0);
        float4 bb = *(const float4*)(ln_b + c0);
        float4 y;
        y.x = bftrunc((xv[k].x - mean) * rstd * g.x + bb.x);
        y.y = bftrunc((xv[k].y - mean) * rstd * g.y + bb.y);
        y.z = bftrunc((xv[k].z - mean) * rstd * g.z + bb.z);
        y.w = bftrunc((xv[k].w - mean) * rstd * g.w + bb.w);
        drow[c0 >> 2] = y;                             // still 128B segments per row
    }
}

extern "C" void kernel_launch(void* const* d_in, const int* in_sizes, int n_in,
                              void* d_out, int out_size, void* d_ws, size_t ws_size,
                              hipStream_t stream) {
    const float* X        = (const float*)d_in[0];
    const float* mask     = (const float*)d_in[1];
    const int*   residx   = (const int*)d_in[2];
    const int*   chains   = (const int*)d_in[3];
    const float* pe_w     = (const float*)d_in[4];
    const float* pe_b     = (const float*)d_in[5];
    const float* edge_w   = (const float*)d_in[6];
    const float* ln_s     = (const float*)d_in[7];
    const float* ln_b     = (const float*)d_in[8];
    char* ws = (char*)d_ws;
    float4* atoms = (float4*)(ws + WS_ATOMS);
    u16*    Wb    = (u16*)(ws + WS_WB);
    u16*    petab = (u16*)(ws + WS_PETAB);
    int*    eidx  = (int*)(ws + WS_EIDX);
    float*  dnb   = (float*)(ws + WS_DNB);
    float* outF = (float*)d_out;
    float* outI = outF + EIDX_OFF;

    k_prep_r26<<<245, 256, 0, stream>>>(X, edge_w, pe_w, pe_b, atoms, Wb, petab);
    k_knn_r26<<<2048, 256, 0, stream>>>(atoms, mask, eidx, dnb, outI);
    k_edge_r26<<<12288, 256, 0, stream>>>(atoms, eidx, dnb, residx, chains, Wb,
                                          petab, ln_s, ln_b, outF);
}